// Round 12
// baseline (5328.072 us; speedup 1.0000x reference)
//
#include <hip/hip_runtime.h>
#include <stdint.h>
#include <stddef.h>

#define NB 1024
#define TB 1024
#define D_IN 6
#define UNITS 64
#define WIDTH 128
#define DOUT 6
#define EPSF 1e-8f
#define SPB 2           // samples OWNED per block (rows 0-1; rows 2-15 are ghosts)
#define ROWS 16         // MFMA tile rows (geometry unchanged)
#define LDK0 108        // c0 row stride (halfs): conflict-free (54 dw == 22 mod 32)
#define LDK 140         // cP/cQ/cG row stride (halfs): conflict-free (70 dw == 6 mod 32)

typedef _Float16 v8h __attribute__((ext_vector_type(8)));
typedef float v4f __attribute__((ext_vector_type(4)));
typedef float v2f __attribute__((ext_vector_type(2)));

#define MFMAH(A,Bf,C) __builtin_amdgcn_mfma_f32_16x16x32_f16((A),(Bf),(C),0,0,0)

// LDS-only barrier: orders LDS across the block, does NOT drain vmcnt.
#define BARRIER_LDS() asm volatile("s_waitcnt lgkmcnt(0)\n\ts_barrier" ::: "memory")

#define C2L2E  2.8853900817779268f    // 2*log2(e)
#define L2E    1.4426950408889634f    // log2(e)
#define NEGL2E (-1.4426950408889634f)

__device__ __forceinline__ float rcp_fast(float x){ return __builtin_amdgcn_rcpf(x); }

// tanh with the 2log2e factor PRE-FOLDED into weights+bias:
// tanh(y) = 1 - 2/(1 + 2^(y*2log2e)); caller passes a2 = y*2log2e (from MFMA).
__device__ __forceinline__ float tanh_from_arg(float a2){
  float u = __builtin_amdgcn_exp2f(a2);
  return fmaf(-2.0f, rcp_fast(u + 1.0f), 1.0f);
}

__device__ __forceinline__ void make_frag1(const float* vals, v8h& hv){
  #pragma unroll
  for (int j = 0; j < 8; j++) hv[j] = (_Float16)vals[j];
}
__device__ __forceinline__ void make_frag2(const float* vals, v8h& hv, v8h& lv){
  #pragma unroll
  for (int j = 0; j < 8; j++){
    _Float16 h = (_Float16)vals[j];
    hv[j] = h;
    lv[j] = (_Float16)(vals[j] - (float)h);
  }
}

// ===== Cross-block desync design =====
// 512 blocks x 256 threads (4 waves). LDS 60KB/block -> exactly 2 blocks/CU
// (160/60 = 2.6); 8 waves/CU = 2 waves/SIMD, ONE FROM EACH BLOCK. The two
// SIMD-mate waves share no barrier -> instruction streams drift anti-phase and
// overlap pipes (the convoy-breaker every within-block attempt failed to get).
// Each wave owns 32 cols (2 groups, shared activation ds_reads) for A/B/C and
// 16 units for D; wave1 adds x-norm, wave2 adds wout. SPB=2: tails run r<2.
// Ghost rows (2-15) are bounded (tanh in [-1,1], ghost nrm=0), row-local
// through every GEMM, and all global stores are masked.
// Register budget: B0+B1+B2+Bah in regs (~192); Bal/Bbh/Woh live in per-lane
// LDS frag arrays ([idx][tid][8], 16B lane stride = conflict-free) -> ~237/wave.
__global__ __launch_bounds__(256, 2) void lmsc_kernel(
    const float* __restrict__ x, const float* __restrict__ initF,
    const float* __restrict__ w10, const float* __restrict__ b10,
    const float* __restrict__ w20, const float* __restrict__ b20,
    const float* __restrict__ w11, const float* __restrict__ b11,
    const float* __restrict__ w21, const float* __restrict__ b21,
    const float* __restrict__ w12, const float* __restrict__ b12,
    const float* __restrict__ w22, const float* __restrict__ b22,
    const float* __restrict__ wa, const float* __restrict__ ba,
    const float* __restrict__ wb, const float* __restrict__ bb,
    const float* __restrict__ wo,
    float* __restrict__ outs, float* __restrict__ alph)
{
  // ---- LDS: 60.0 KB total -> caps residency at 2 blocks/CU ----
  __shared__ __attribute__((aligned(16))) _Float16 c0[2][ROWS*LDK0];   // 6912 B
  __shared__ __attribute__((aligned(16))) _Float16 cP[ROWS*LDK];       // 4480 B
  __shared__ __attribute__((aligned(16))) _Float16 cQ[ROWS*LDK];
  __shared__ __attribute__((aligned(16))) _Float16 cG[ROWS*LDK];
  __shared__ __attribute__((aligned(16))) _Float16 fragD[8][256][8];   // 32768 B: Bal[0..3], Bbh[4..7]
  __shared__ __attribute__((aligned(16))) _Float16 fragW[2][256][8];   // 8192 B: wout frags
  __shared__ __attribute__((aligned(16))) float nrm[2][ROWS];          // -log2e*||x||; ghosts 0

  const int tid = threadIdx.x;
  const int wv = tid >> 6;       // wave 0..3
  const int ln = tid & 63;
  const int mn = ln & 15;
  const int qd = ln >> 4;
  const int q8 = qd * 8;
  const int n0 = wv * 16 + mn;   // col group 0 (0..63)
  const int n1 = n0 + 64;        // col group 1 (64..127)
  const int u  = wv * 16 + mn;   // D-phase unit (0..63)
  const int sgbase = (int)blockIdx.x * SPB;

  float tmp[8];

  // ---------------- weight fragments ----------------
  // exp2-feeding weights PRE-SCALED (L0/L1 both br, L2 br0: *2log2e; wa: *log2e;
  // wb: *2log2e). f16 rounding is scale-invariant -> no accuracy change.
  v8h B0[2][3][2];
  #pragma unroll
  for (int g = 0; g < 2; g++)
    #pragma unroll
    for (int kf = 0; kf < 3; kf++)
      #pragma unroll
      for (int br = 0; br < 2; br++){
        const float* W = br ? w20 : w10;
        const int nc = g ? n1 : n0;
        #pragma unroll
        for (int j = 0; j < 8; j++){
          int k = kf*32 + q8 + j;
          int r = (k < 6) ? k : ((k >= 8 && k < 72) ? (k - 2) : -1);
          tmp[j] = (r >= 0) ? W[r*WIDTH + nc] * C2L2E : 0.0f;
        }
        make_frag1(tmp, B0[g][kf][br]);
      }

  v8h B1[2][4][2], B2[2][4][2];
  #pragma unroll
  for (int g = 0; g < 2; g++)
    #pragma unroll
    for (int kf = 0; kf < 4; kf++)
      #pragma unroll
      for (int br = 0; br < 2; br++){
        const int nc = g ? n1 : n0;
        const float* W = br ? w21 : w11;
        #pragma unroll
        for (int j = 0; j < 8; j++)
          tmp[j] = W[(kf*32 + q8 + j)*WIDTH + nc] * C2L2E;
        make_frag1(tmp, B1[g][kf][br]);
        const float* V = br ? w22 : w12;
        const float sc = br ? 1.0f : C2L2E;
        #pragma unroll
        for (int j = 0; j < 8; j++)
          tmp[j] = V[(kf*32 + q8 + j)*WIDTH + nc] * sc;
        make_frag1(tmp, B2[g][kf][br]);
      }

  // D frags: Bah in registers; Bal, Bbh spill-proofed to per-lane LDS
  v8h Bah[4];
  #pragma unroll
  for (int kf = 0; kf < 4; kf++){
    #pragma unroll
    for (int j = 0; j < 8; j++)
      tmp[j] = wa[(kf*32 + q8 + j)*UNITS + u] * L2E;
    v8h lv;
    make_frag2(tmp, Bah[kf], lv);
    *(v8h*)&fragD[kf][tid][0] = lv;
    #pragma unroll
    for (int j = 0; j < 8; j++)
      tmp[j] = wb[(kf*32 + q8 + j)*UNITS + u] * C2L2E;
    v8h bv;
    make_frag1(tmp, bv);
    *(v8h*)&fragD[4 + kf][tid][0] = bv;
  }
  const float bsa = ba[u] * L2E;     // alpha = exp2(pA)
  const float bsb = bb[u] * C2L2E;   // beta  = tanh_from_arg(pB)

  // wout frags -> LDS (used by wave 2)
  {
    #pragma unroll
    for (int j = 0; j < 8; j++)
      tmp[j] = (mn < DOUT) ? wo[(q8 + j)*DOUT + mn] : 0.0f;
    v8h w0h; make_frag1(tmp, w0h);
    *(v8h*)&fragW[0][tid][0] = w0h;
    #pragma unroll
    for (int j = 0; j < 8; j++)
      tmp[j] = (mn < DOUT) ? wo[(32 + q8 + j)*DOUT + mn] : 0.0f;
    v8h w1h; make_frag1(tmp, w1h);
    *(v8h*)&fragW[1][tid][0] = w1h;
  }

  // biases (exp2-arg scale) per col-group
  const float e0a[2] = {b10[n0]*C2L2E, b10[n1]*C2L2E};
  const float e0b[2] = {b20[n0]*C2L2E, b20[n1]*C2L2E};
  const float e1a[2] = {b11[n0]*C2L2E, b11[n1]*C2L2E};
  const float e1b[2] = {b21[n0]*C2L2E, b21[n1]*C2L2E};
  const float e2a[2] = {b12[n0]*C2L2E, b12[n1]*C2L2E};
  const float e2b[2] = {b22[n0],       b22[n1]};

  // global-store bases (only qd==0 lanes dereference; samples 0..1)
  float* alp  = alph + ((size_t)sgbase * TB) * UNITS + u;     // all waves, qd==0
  float* outp = outs + ((size_t)sgbase * TB) * DOUT + mn;     // wave 2, qd==0

  // ---------------- init ----------------
  for (int i = tid; i < 2*ROWS*LDK0; i += 256) c0[0][i] = (_Float16)0.0f;
  if (tid < ROWS){ nrm[0][tid] = 0.0f; nrm[1][tid] = 0.0f; }
  __syncthreads();

  // h persistent in registers: qd==0 lanes hold samples 0..1; ghosts = 0
  float hreg[SPB] = {0.0f, 0.0f};
  if (qd == 0){
    #pragma unroll
    for (int r = 0; r < SPB; r++){
      float v = initF[(size_t)(sgbase + r)*(2 + UNITS) + 2 + u];
      hreg[r] = v;
      c0[0][r*LDK0 + 8 + u] = (_Float16)v;
    }
  }
  float xv0=0, xv1=0, xv2=0, xv3=0, xv4=0, xv5=0;
  if (wv == 1 && ln < SPB){
    const v2f* xp2 = (const v2f*)(x + (size_t)(sgbase + ln)*TB*D_IN);  // rows 24B -> 8B aligned
    v2f A = xp2[0], Bv = xp2[1], C = xp2[2];
    float nv = sqrtf(A[0]*A[0] + A[1]*A[1] + Bv[0]*Bv[0] + Bv[1]*Bv[1] + C[0]*C[0] + C[1]*C[1]);
    nrm[0][ln] = nv * NEGL2E;
    float inv = 1.0f / (nv + EPSF);
    c0[0][ln*LDK0 + 0] = (_Float16)(A[0]*inv);
    c0[0][ln*LDK0 + 1] = (_Float16)(A[1]*inv);
    c0[0][ln*LDK0 + 2] = (_Float16)(Bv[0]*inv);
    c0[0][ln*LDK0 + 3] = (_Float16)(Bv[1]*inv);
    c0[0][ln*LDK0 + 4] = (_Float16)(C[0]*inv);
    c0[0][ln*LDK0 + 5] = (_Float16)(C[1]*inv);
    v2f D = xp2[3], E = xp2[4], F = xp2[5];                            // x(t=1)
    xv0 = D[0]; xv1 = D[1]; xv2 = E[0]; xv3 = E[1]; xv4 = F[0]; xv5 = F[1];
  }
  __syncthreads();

  auto wout_phase = [&](const _Float16* cb, int tt){
    v8h ah0 = *(const v8h*)(cb + mn*LDK0 + 8 + q8);
    v8h ah1 = *(const v8h*)(cb + mn*LDK0 + 40 + q8);
    v8h W0 = *(const v8h*)&fragW[0][tid][0];
    v8h W1 = *(const v8h*)&fragW[1][tid][0];
    v4f acc = {0.f, 0.f, 0.f, 0.f};
    acc = MFMAH(ah0, W0, acc);
    acc = MFMAH(ah1, W1, acc);
    if (mn < DOUT && qd == 0){
      #pragma unroll
      for (int r = 0; r < SPB; r++)
        outp[(size_t)r*TB*DOUT + (size_t)tt*DOUT] = acc[r];
    }
  };

  // ================= time loop (4 LDS-only barriers/step) =================
  for (int t = 0; t < TB; t++){
    const int p = t & 1;
    const _Float16* c0r = c0[p];
    _Float16* c0w = c0[p ^ 1];

    // ---- Phase A: L0 (c0[p] -> cP); one ah read feeds BOTH col-groups ----
    {
      v8h ah[3];
      #pragma unroll
      for (int kf = 0; kf < 3; kf++)
        ah[kf] = *(const v8h*)(c0r + mn*LDK0 + kf*32 + q8);
      v4f a0[2], a1[2];
      #pragma unroll
      for (int g = 0; g < 2; g++){
        a0[g] = (v4f){e0a[g], e0a[g], e0a[g], e0a[g]};
        a1[g] = (v4f){e0b[g], e0b[g], e0b[g], e0b[g]};
      }
      #pragma unroll
      for (int kf = 0; kf < 3; kf++)
        #pragma unroll
        for (int g = 0; g < 2; g++){
          a0[g] = MFMAH(ah[kf], B0[g][kf][0], a0[g]);
          a1[g] = MFMAH(ah[kf], B0[g][kf][1], a1[g]);
        }
      // tanh(y1)*tanh(y2) = (p-s+1)/(p+s+1), u_i = 2^arg_i straight from MFMA.
      #pragma unroll
      for (int g = 0; g < 2; g++)
        #pragma unroll
        for (int r = 0; r < SPB; r++){
          float u0 = __builtin_amdgcn_exp2f(a0[g][r]);
          float u1 = __builtin_amdgcn_exp2f(a1[g][r]);
          float pp = fmaf(u0, u1, 1.0f);
          float sm = u0 + u1;
          cP[(qd*4 + r)*LDK + (g ? n1 : n0)] = (_Float16)((pp - sm) * rcp_fast(pp + sm));
        }
    }
    BARRIER_LDS();  // b1

    // ---- Phase B: L1 (cP -> cQ) ----
    {
      v8h ah[4];
      #pragma unroll
      for (int kf = 0; kf < 4; kf++)
        ah[kf] = *(const v8h*)(cP + mn*LDK + kf*32 + q8);
      v4f a0[2], a1[2];
      #pragma unroll
      for (int g = 0; g < 2; g++){
        a0[g] = (v4f){e1a[g], e1a[g], e1a[g], e1a[g]};
        a1[g] = (v4f){e1b[g], e1b[g], e1b[g], e1b[g]};
      }
      #pragma unroll
      for (int kf = 0; kf < 4; kf++)
        #pragma unroll
        for (int g = 0; g < 2; g++){
          a0[g] = MFMAH(ah[kf], B1[g][kf][0], a0[g]);
          a1[g] = MFMAH(ah[kf], B1[g][kf][1], a1[g]);
        }
      #pragma unroll
      for (int g = 0; g < 2; g++)
        #pragma unroll
        for (int r = 0; r < SPB; r++){
          float u0 = __builtin_amdgcn_exp2f(a0[g][r]);
          float u1 = __builtin_amdgcn_exp2f(a1[g][r]);
          float pp = fmaf(u0, u1, 1.0f);
          float sm = u0 + u1;
          cQ[(qd*4 + r)*LDK + (g ? n1 : n0)] = (_Float16)((pp - sm) * rcp_fast(pp + sm));
        }
    }
    BARRIER_LDS();  // b2

    // ---- Phase C: L2 (cQ -> cG), g = tanh(x1*x2) ----
    {
      v8h ah[4];
      #pragma unroll
      for (int kf = 0; kf < 4; kf++)
        ah[kf] = *(const v8h*)(cQ + mn*LDK + kf*32 + q8);
      v4f a0[2], a1[2];
      #pragma unroll
      for (int g = 0; g < 2; g++){
        a0[g] = (v4f){e2a[g], e2a[g], e2a[g], e2a[g]};
        a1[g] = (v4f){e2b[g], e2b[g], e2b[g], e2b[g]};
      }
      #pragma unroll
      for (int kf = 0; kf < 4; kf++)
        #pragma unroll
        for (int g = 0; g < 2; g++){
          a0[g] = MFMAH(ah[kf], B2[g][kf][0], a0[g]);
          a1[g] = MFMAH(ah[kf], B2[g][kf][1], a1[g]);
        }
      #pragma unroll
      for (int g = 0; g < 2; g++)
        #pragma unroll
        for (int r = 0; r < SPB; r++)
          cG[(qd*4 + r)*LDK + (g ? n1 : n0)] = (_Float16)tanh_from_arg(a0[g][r] * a1[g][r]);
    }
    BARRIER_LDS();  // b3

    // ---- Phase D: all 4 waves (16 units each); wave1 += xnorm, wave2 += wout ----
    {
      v8h gh[4];
      #pragma unroll
      for (int kf = 0; kf < 4; kf++)
        gh[kf] = *(const v8h*)(cG + mn*LDK + kf*32 + q8);
      v8h BalL[4], BbhL[4];
      #pragma unroll
      for (int kf = 0; kf < 4; kf++){
        BalL[kf] = *(const v8h*)&fragD[kf][tid][0];
        BbhL[kf] = *(const v8h*)&fragD[4 + kf][tid][0];
      }
      v4f pA0 = {bsa, bsa, bsa, bsa};
      v4f pA1 = {0.f, 0.f, 0.f, 0.f};
      v4f pB  = {bsb, bsb, bsb, bsb};
      #pragma unroll
      for (int kf = 0; kf < 2; kf++){
        pA0 = MFMAH(gh[kf], Bah[kf], pA0);
        pA0 = MFMAH(gh[kf], BalL[kf], pA0);
        pA1 = MFMAH(gh[kf+2], Bah[kf+2], pA1);
        pA1 = MFMAH(gh[kf+2], BalL[kf+2], pA1);
        pB  = MFMAH(gh[2*kf],   BbhL[2*kf],   pB);
        pB  = MFMAH(gh[2*kf+1], BbhL[2*kf+1], pB);
      }
      #pragma unroll
      for (int r = 0; r < SPB; r++){
        float m = nrm[p][qd*4 + r];                            // ghosts read 0 -> dec=1, bounded
        float alpha = __builtin_amdgcn_exp2f(pA0[r] + pA1[r]); // wa,ba pre-scaled
        float beta  = tanh_from_arg(pB[r]);                    // wb,bb pre-scaled
        float dec   = __builtin_amdgcn_exp2f(alpha * m);       // exp(-alpha*norm)
        float h = fmaf(dec, hreg[r] - beta, beta);
        hreg[r] = h;
        c0w[(qd*4 + r)*LDK0 + 8 + u] = (_Float16)h;            // ghost rows: bounded garbage
        if (qd == 0) alp[(size_t)r*TB*UNITS] = alpha;
      }
      alp += UNITS;
    }
    if (wv == 1 && ln < SPB){
      float nv2 = sqrtf(xv0*xv0 + xv1*xv1 + xv2*xv2 + xv3*xv3 + xv4*xv4 + xv5*xv5);
      nrm[p ^ 1][ln] = nv2 * NEGL2E;
      float inv = 1.0f / (nv2 + EPSF);
      c0w[ln*LDK0 + 0] = (_Float16)(xv0*inv);
      c0w[ln*LDK0 + 1] = (_Float16)(xv1*inv);
      c0w[ln*LDK0 + 2] = (_Float16)(xv2*inv);
      c0w[ln*LDK0 + 3] = (_Float16)(xv3*inv);
      c0w[ln*LDK0 + 4] = (_Float16)(xv4*inv);
      c0w[ln*LDK0 + 5] = (_Float16)(xv5*inv);
      int tn = t + 2; if (tn > TB - 1) tn = TB - 1;
      const v2f* xp2 = (const v2f*)(x + ((size_t)(sgbase + ln)*TB + (size_t)tn)*D_IN);
      v2f D = xp2[0], E = xp2[1], F = xp2[2];
      xv0 = D[0]; xv1 = D[1]; xv2 = E[0]; xv3 = E[1]; xv4 = F[0]; xv5 = F[1];
    } else if (wv == 2){
      if (t > 0) wout_phase(c0r, t - 1);
    }
    BARRIER_LDS();  // b4
  }

  // final wout(TB-1): h(TB-1) sits in c0[0] (TB even)
  if (wv == 2) wout_phase(c0[0], TB - 1);
}

extern "C" void kernel_launch(void* const* d_in, const int* in_sizes, int n_in,
                              void* d_out, int out_size, void* d_ws, size_t ws_size,
                              hipStream_t stream) {
  const float* x    = (const float*)d_in[0];
  const float* iF   = (const float*)d_in[1];
  const float* w10  = (const float*)d_in[2];
  const float* b10  = (const float*)d_in[3];
  const float* w20  = (const float*)d_in[4];
  const float* b20  = (const float*)d_in[5];
  const float* w11  = (const float*)d_in[6];
  const float* b11  = (const float*)d_in[7];
  const float* w21  = (const float*)d_in[8];
  const float* b21  = (const float*)d_in[9];
  const float* w12  = (const float*)d_in[10];
  const float* b12  = (const float*)d_in[11];
  const float* w22  = (const float*)d_in[12];
  const float* b22  = (const float*)d_in[13];
  const float* wa   = (const float*)d_in[14];
  const float* ba   = (const float*)d_in[15];
  const float* wb   = (const float*)d_in[16];
  const float* bb   = (const float*)d_in[17];
  const float* wo   = (const float*)d_in[18];

  float* outs = (float*)d_out;
  float* alph = outs + (size_t)NB*TB*DOUT;

  lmsc_kernel<<<NB/SPB, 256, 0, stream>>>(x, iF,
      w10, b10, w20, b20, w11, b11, w21, b21, w12, b12, w22, b22,
      wa, ba, wb, bb, wo, outs, alph);
}